// Round 1
// baseline (286.901 us; speedup 1.0000x reference)
//
#include <hip/hip_runtime.h>

// ---------------- fast device math ----------------
__device__ __forceinline__ float fdiv_fast(float a, float b) {
    return __fdividef(a, b);
}

__device__ __forceinline__ float tanh_fast(float x) {
    // tanh(x) = (e^{2x}-1)/(e^{2x}+1); clamp to avoid inf/inf
    float t = fminf(fmaxf(2.0f * x, -80.0f), 80.0f);
    float e = __expf(t);
    return fdiv_fast(e - 1.0f, e + 1.0f);
}

__device__ __forceinline__ float asinh_pos(float x) {
    // x >= 0 in this problem (current i in [1,3] A)
    return __logf(x + sqrtf(fmaf(x, x, 1.0f)));
}

// physical constants (match reference, f32)
#define RTF     (8.3144621f / 96487.0f)   // R/F
#define VOL_    2.2e-05f
#define VOLS_   2.2e-06f                  // 0.1*VOL
#define VOLB_   1.98e-05f                 // VOL - VOLS
#define INV_TDIFF (1.0f / 7.0e6f)

__global__ __launch_bounds__(256) void battery_cell_kernel(
    const float* __restrict__ inp,   // [B] current
    const float* __restrict__ st,    // [B,8] states
    const float* __restrict__ qMaxp, // [B]
    const float* __restrict__ Rop,   // [B]
    const float* __restrict__ Wp0,   // [8,1]
    const float* __restrict__ bp0,   // [8]
    const float* __restrict__ Wp2,   // [4,8]
    const float* __restrict__ bp2,   // [4]
    const float* __restrict__ Wp4,   // [1,4]
    const float* __restrict__ bp4,   // [1]
    const float* __restrict__ Wn,    // [1,1]
    const float* __restrict__ bn,    // [1]
    float* __restrict__ outV,        // [B]
    float* __restrict__ outX,        // [B,8]
    int B)
{
    int b = blockIdx.x * blockDim.x + threadIdx.x;
    if (b >= B) return;

    // ---- loads (coalesced; states as 2x float4) ----
    const float4* st4 = (const float4*)st;
    float4 s0 = st4[2 * b];
    float4 s1 = st4[2 * b + 1];
    float Tb  = s0.x, Vo  = s0.y, Vsn = s0.z, Vsp = s0.w;
    float qnB = s1.x, qnS = s1.y, qpB = s1.z, qpS = s1.w;
    float i   = inp[b];
    float qm  = qMaxp[b];
    float ro  = Rop[b];

    // wave-uniform weights (scalar-load friendly)
    float w0[8], b0v[8], w2v[32], b2v[4], w4v[4];
#pragma unroll
    for (int j = 0; j < 8; j++) { w0[j] = Wp0[j]; b0v[j] = bp0[j]; }
#pragma unroll
    for (int j = 0; j < 32; j++) w2v[j] = Wp2[j];
#pragma unroll
    for (int j = 0; j < 4; j++)  { b2v[j] = bp2[j]; w4v[j] = Wp4[j]; }
    float wb4 = bp4[0], wn = Wn[0], wbn = bn[0];

    // ---- getNextState ----
    float qSMax = qm * 1000.0f;               // qMax*QMAX_BASE*VOLS/VOL
    float invq  = fdiv_fast(1.0f, qSMax);

    float xpS = fminf(fmaxf(qpS * invq, 1e-18f), 1.0f);
    float xnS = fminf(fmaxf(qnS * invq, 1e-18f), 1.0f);
    float Jn0 = 1e-18f + 20000.0f * sqrtf((1.0f - xnS) * xnS);
    float Jp0 = 1e-18f + 20000.0f * sqrtf((1.0f - xpS) * xpS);

    float qdotn = (qnB * (1.0f / VOLB_) - qnS * (1.0f / VOLS_)) * INV_TDIFF;
    float qdotp = (qpB * (1.0f / VOLB_) - qpS * (1.0f / VOLS_)) * INV_TDIFF;

    float Jn = i * 5000.0f;                   // i/SN
    float Jp = i * 5000.0f;                   // i/SP
    float VoNom  = i * ro * 10.0f;            // i*Ro*RoBASE
    float coef   = RTF * Tb * 2.0f;           // R*Tb/F/ALPHA
    float VsnNom = coef * asinh_pos(fdiv_fast(Jn, 2.0f * Jn0));
    float VspNom = coef * asinh_pos(fdiv_fast(Jp, 2.0f * Jp0));

    float Vo2  = Vo  + (VoNom  - Vo ) * 0.1f;
    float Vsn2 = Vsn + (VsnNom - Vsn) * (1.0f / 90.0f);
    float Vsp2 = Vsp + (VspNom - Vsp) * (1.0f / 90.0f);
    float qnB2 = qnB - qdotn;
    float qnS2 = qnS + qdotn - i;
    float qpB2 = qpB - qdotp;
    float qpS2 = qpS + i + qdotp;

    // ---- getNextOutput (on XNew) ----
    float xp = qpS2 * invq;   // unclipped, as in reference
    float xn = qnS2 * invq;

    // MLP: tanh(x*Wp0+bp0) -> tanh(h@Wp2.T+bp2) -> @Wp4.T+bp4
    float h1[8];
#pragma unroll
    for (int j = 0; j < 8; j++)
        h1[j] = tanh_fast(fmaf(xp, w0[j], b0v[j]));
    float vep_mlp = wb4;
#pragma unroll
    for (int k = 0; k < 4; k++) {
        float a = b2v[k];
#pragma unroll
        for (int j = 0; j < 8; j++)
            a = fmaf(h1[j], w2v[k * 8 + j], a);
        vep_mlp = fmaf(tanh_fast(a), w4v[k], vep_mlp);
    }
    float ven_mlp = fmaf(xn, wn, wbn);

    float rp = fminf(fmaxf(fdiv_fast(1.0f - xp, xp), 1e-18f), 1e18f);
    float rn = fminf(fmaxf(fdiv_fast(1.0f - xn, xn), 1e-18f), 1e18f);
    float rtb = RTF * Tb;   // Tb2 == Tb
    float Vep = 4.03f + rtb * __logf(rp) + vep_mlp;
    float Ven = 0.01f + rtb * __logf(rn) + ven_mlp;
    float V = Vep - Ven - Vo2 - Vsn2 - Vsp2;

    // ---- stores ----
    outV[b] = V;
    float4 o0 = make_float4(Tb, Vo2, Vsn2, Vsp2);
    float4 o1 = make_float4(qnB2, qnS2, qpB2, qpS2);
    float4* ox4 = (float4*)outX;
    ox4[2 * b]     = o0;
    ox4[2 * b + 1] = o1;
}

extern "C" void kernel_launch(void* const* d_in, const int* in_sizes, int n_in,
                              void* d_out, int out_size, void* d_ws, size_t ws_size,
                              hipStream_t stream) {
    const float* inp  = (const float*)d_in[0];
    const float* st   = (const float*)d_in[1];
    const float* qMax = (const float*)d_in[2];
    const float* Ro   = (const float*)d_in[3];
    const float* Wp0  = (const float*)d_in[4];
    const float* bp0  = (const float*)d_in[5];
    const float* Wp2  = (const float*)d_in[6];
    const float* bp2  = (const float*)d_in[7];
    const float* Wp4  = (const float*)d_in[8];
    const float* bp4  = (const float*)d_in[9];
    const float* Wn   = (const float*)d_in[10];
    const float* bn   = (const float*)d_in[11];

    int B = in_sizes[0];
    float* outV = (float*)d_out;          // [B]
    float* outX = (float*)d_out + B;      // [B,8]  (16B-aligned: B*4 % 16 == 0)

    int block = 256;
    int grid = (B + block - 1) / block;
    battery_cell_kernel<<<grid, block, 0, stream>>>(
        inp, st, qMax, Ro, Wp0, bp0, Wp2, bp2, Wp4, bp4, Wn, bn,
        outV, outX, B);
}